// Round 1
// baseline (1674.281 us; speedup 1.0000x reference)
//
#include <hip/hip_runtime.h>

#define B_ 8
#define T_ 32
#define N_ 500
#define DP 200
#define DC 128
#define H_ 4
#define U_ 64
// MSG_UNITS == U_ == 64; out columns per (t): 64; msg row length T_*U_ = 2048

// ---------------------------------------------------------------------------
// Kernel A: h_src[b,n,u], h_dst[b,n,u] for one head.
// block = 128 threads per (b,n): threads 0-63 -> src, 64-127 -> dst.
__global__ void __launch_bounds__(128) proj_src_dst(
    const float* __restrict__ prev,   // [B,N,DP]
    const float* __restrict__ Wsrc,   // [H,DP,U]
    const float* __restrict__ Wdst,   // [H,DP,U]
    float* __restrict__ hsrc,         // [B*N,U]
    float* __restrict__ hdst,         // [B*N,U]
    int h)
{
    __shared__ float row[DP];
    const int bn  = blockIdx.x;
    const int tid = threadIdx.x;
    const float* p = prev + (size_t)bn * DP;
    for (int i = tid; i < DP; i += 128) row[i] = p[i];
    __syncthreads();
    const float* W = ((tid < 64) ? Wsrc : Wdst) + (size_t)h * DP * U_;
    const int u = tid & 63;
    float acc = 0.f;
#pragma unroll 8
    for (int d = 0; d < DP; ++d) acc = fmaf(row[d], W[d * U_ + u], acc);
    float* o = (tid < 64) ? hsrc : hdst;
    o[(size_t)bn * U_ + u] = acc;
}

// ---------------------------------------------------------------------------
// Kernel B: scores + softmax -> attn[b,i,j] for one head.
// block = 512 threads per (b,i); thread j computes score(i,j).
__global__ void __launch_bounds__(512) attn_softmax(
    const float* __restrict__ hsrc,   // [B*N,U]
    const float* __restrict__ hdst,   // [B*N,U]
    const float* __restrict__ a_all,  // [H,U]
    float* __restrict__ attn,         // [B,N,N]
    int h)
{
    const int i   = blockIdx.x;
    const int b   = blockIdx.y;
    const int tid = threadIdx.x;

    __shared__ float s_src[U_];
    __shared__ float s_a[U_];
    __shared__ float wred[8];
    __shared__ float s_max, s_sum;

    if (tid < U_) {
        s_src[tid] = hsrc[((size_t)b * N_ + i) * U_ + tid];
        s_a[tid]   = a_all[h * U_ + tid];
    }
    __syncthreads();

    float score = -1e30f;
    if (tid < N_) {
        const float* dst = hdst + ((size_t)b * N_ + tid) * U_;
        float s = 0.f;
#pragma unroll 8
        for (int u = 0; u < U_; ++u) {
            float x = s_src[u] + dst[u];
            x = (x >= 0.f) ? x : 0.2f * x;
            s = fmaf(x, s_a[u], s);
        }
        score = s;
    }

    const int wave = tid >> 6, lane = tid & 63;
    // max reduce
    float m = score;
    for (int off = 1; off < 64; off <<= 1) m = fmaxf(m, __shfl_xor(m, off));
    if (lane == 0) wred[wave] = m;
    __syncthreads();
    if (tid == 0) {
        float mm = wred[0];
        for (int w = 1; w < 8; ++w) mm = fmaxf(mm, wred[w]);
        s_max = mm;
    }
    __syncthreads();
    float e = (tid < N_) ? __expf(score - s_max) : 0.f;
    // sum reduce
    float sm = e;
    for (int off = 1; off < 64; off <<= 1) sm += __shfl_xor(sm, off);
    __syncthreads();  // protect wred reuse
    if (lane == 0) wred[wave] = sm;
    __syncthreads();
    if (tid == 0) {
        float ss = 0.f;
        for (int w = 0; w < 8; ++w) ss += wred[w];
        s_sum = ss;
    }
    __syncthreads();
    if (tid < N_) attn[((size_t)b * N_ + i) * N_ + tid] = e / s_sum;
}

// ---------------------------------------------------------------------------
// Kernel C: msg[b, m, t*64+u] = sum_d curr[b,t,m,d] * Wmsg_h[d,u]
// block = 256 threads per (b, t, m-block of 4). W_msg staged in LDS.
__global__ void __launch_bounds__(256) msg_proj(
    const float* __restrict__ curr,   // [B,T,N,DC]
    const float* __restrict__ Wh,     // [DC,U] (head already offset)
    float* __restrict__ msg)          // [B, N(m), T*U]
{
    __shared__ float Wl[DC * U_];     // 32 KiB
    __shared__ float cl[4][DC];       // 2 KiB
    const int tid = threadIdx.x;
    const int m0 = blockIdx.x * 4, t = blockIdx.y, b = blockIdx.z;

    for (int i = tid; i < DC * U_; i += 256) Wl[i] = Wh[i];
    const float* cbase = curr + (((size_t)(b * T_ + t)) * N_ + m0) * DC;
    for (int i = tid; i < 4 * DC; i += 256) cl[i >> 7][i & 127] = cbase[i];
    __syncthreads();

    const int lm = tid >> 6, u = tid & 63;
    float acc = 0.f;
#pragma unroll 8
    for (int d = 0; d < DC; ++d) acc = fmaf(cl[lm][d], Wl[d * U_ + u], acc);
    const int m = m0 + lm;
    msg[((size_t)b * N_ + m) * (T_ * U_) + t * U_ + u] = acc;
}

// ---------------------------------------------------------------------------
// Kernel D: out[b,t,n,u] (+)= 0.25 * sum_m attn[b,n,m] * msg[b,m,t*64+u]
// Tiled SGEMM: per (b): C[500 x 2048] = A[500 x 500] @ Bm[500 x 2048]
// BM=64 (n), BN=64 (one t: u=0..63), BK=16; 256 threads, 4x4 microtile.
__global__ void __launch_bounds__(256) gemm_acc(
    const float* __restrict__ attn,   // [B,N,N]
    const float* __restrict__ msg,    // [B,N,T*U]
    float* __restrict__ out,          // [B,T,N,U]
    int init)
{
    __shared__ float As[16][68];      // padded: +4 kills write conflicts
    __shared__ float Bs[16][64];

    const int i0 = blockIdx.x * 64;   // n tile
    const int t  = blockIdx.y;
    const int b  = blockIdx.z;
    const int tid = threadIdx.x;
    const int ty = tid >> 4, tx = tid & 15;

    const float* A  = attn + (size_t)b * N_ * N_;
    const float* Bm = msg + (size_t)b * N_ * (T_ * U_) + t * U_;

    float acc[4][4] = {};

    for (int k0 = 0; k0 < N_; k0 += 16) {
#pragma unroll
        for (int r = 0; r < 4; ++r) {
            int idx = r * 256 + tid;
            int i = idx >> 4, k = idx & 15;
            int gi = i0 + i, gk = k0 + k;
            As[k][i] = (gi < N_ && gk < N_) ? A[(size_t)gi * N_ + gk] : 0.f;
        }
#pragma unroll
        for (int r = 0; r < 4; ++r) {
            int idx = r * 256 + tid;
            int k = idx >> 6, c = idx & 63;
            int gk = k0 + k;
            Bs[k][c] = (gk < N_) ? Bm[(size_t)gk * (T_ * U_) + c] : 0.f;
        }
        __syncthreads();
#pragma unroll
        for (int k = 0; k < 16; ++k) {
            const float4 av = *reinterpret_cast<const float4*>(&As[k][ty * 4]);
            const float4 bv = *reinterpret_cast<const float4*>(&Bs[k][tx * 4]);
            const float a0 = av.x, a1 = av.y, a2 = av.z, a3 = av.w;
            const float b0 = bv.x, b1 = bv.y, b2 = bv.z, b3 = bv.w;
            acc[0][0] = fmaf(a0, b0, acc[0][0]);
            acc[0][1] = fmaf(a0, b1, acc[0][1]);
            acc[0][2] = fmaf(a0, b2, acc[0][2]);
            acc[0][3] = fmaf(a0, b3, acc[0][3]);
            acc[1][0] = fmaf(a1, b0, acc[1][0]);
            acc[1][1] = fmaf(a1, b1, acc[1][1]);
            acc[1][2] = fmaf(a1, b2, acc[1][2]);
            acc[1][3] = fmaf(a1, b3, acc[1][3]);
            acc[2][0] = fmaf(a2, b0, acc[2][0]);
            acc[2][1] = fmaf(a2, b1, acc[2][1]);
            acc[2][2] = fmaf(a2, b2, acc[2][2]);
            acc[2][3] = fmaf(a2, b3, acc[2][3]);
            acc[3][0] = fmaf(a3, b0, acc[3][0]);
            acc[3][1] = fmaf(a3, b1, acc[3][1]);
            acc[3][2] = fmaf(a3, b2, acc[3][2]);
            acc[3][3] = fmaf(a3, b3, acc[3][3]);
        }
        __syncthreads();
    }

    const float scale = 0.25f;
#pragma unroll
    for (int aa = 0; aa < 4; ++aa) {
        const int gi = i0 + ty * 4 + aa;
        if (gi < N_) {
            float4* op = reinterpret_cast<float4*>(
                &out[(((size_t)b * T_ + t) * N_ + gi) * U_ + tx * 4]);
            float4 v;
            v.x = acc[aa][0] * scale;
            v.y = acc[aa][1] * scale;
            v.z = acc[aa][2] * scale;
            v.w = acc[aa][3] * scale;
            if (!init) {
                float4 old = *op;
                v.x += old.x; v.y += old.y; v.z += old.z; v.w += old.w;
            }
            *op = v;
        }
    }
}

// ---------------------------------------------------------------------------
extern "C" void kernel_launch(void* const* d_in, const int* in_sizes, int n_in,
                              void* d_out, int out_size, void* d_ws, size_t ws_size,
                              hipStream_t stream)
{
    const float* prev = (const float*)d_in[0];   // [B,N,DP]
    const float* curr = (const float*)d_in[1];   // [B,T,N,DC]
    const float* Wsrc = (const float*)d_in[2];   // [H,DP,U]
    const float* Wdst = (const float*)d_in[3];   // [H,DP,U]
    const float* avec = (const float*)d_in[4];   // [H,U,1]
    const float* Wmsg = (const float*)d_in[5];   // [H,DC,U]
    float* out = (float*)d_out;                  // [B,T,N,U]

    float* ws   = (float*)d_ws;
    float* hsrc = ws;                                     // B*N*U     = 256000
    float* hdst = hsrc + (size_t)B_ * N_ * U_;            // 256000
    float* attn = hdst + (size_t)B_ * N_ * U_;            // B*N*N     = 2,000,000
    float* msg  = attn + (size_t)B_ * N_ * N_;            // B*N*T*U   = 8,192,000
    // total ~42.8 MB of ws, reused across heads

    for (int h = 0; h < H_; ++h) {
        proj_src_dst<<<dim3(B_ * N_), 128, 0, stream>>>(prev, Wsrc, Wdst, hsrc, hdst, h);
        attn_softmax<<<dim3(N_, B_), 512, 0, stream>>>(hsrc, hdst, avec, attn, h);
        msg_proj<<<dim3(N_ / 4, T_, B_), 256, 0, stream>>>(
            curr, Wmsg + (size_t)h * DC * U_, msg);
        gemm_acc<<<dim3(8, T_, B_), 256, 0, stream>>>(attn, msg, out, h == 0 ? 1 : 0);
    }
}

// Round 2
// 402.602 us; speedup vs baseline: 4.1587x; 4.1587x over previous
//
#include <hip/hip_runtime.h>

#define B_ 8
#define T_ 32
#define N_ 500
#define DP 200
#define DC 128
#define H_ 4
#define U_ 64
#define NP 512           // padded N (K and i dims)
#define COLS (T_ * U_)   // 2048

typedef __attribute__((ext_vector_type(8))) short bf16x8;
typedef __attribute__((ext_vector_type(4))) float f32x4;

__device__ __forceinline__ ushort f2bf(float f) {
    unsigned u = __float_as_uint(f);
    unsigned r = (u + 0x7FFFu + ((u >> 16) & 1u)) >> 16;  // RTNE
    return (ushort)r;
}

// ---------------------------------------------------------------------------
__global__ void zero_fill(uint4* __restrict__ p, int n16) {
    int i = blockIdx.x * blockDim.x + threadIdx.x;
    int stride = gridDim.x * blockDim.x;
    uint4 z; z.x = 0; z.y = 0; z.z = 0; z.w = 0;
    for (; i < n16; i += stride) p[i] = z;
}

// WT[h][u][d] = bf16(Wmsg[h][d][u])   (4*64*128 = 32768 elements)
__global__ void prep_wT(const float* __restrict__ Wmsg, ushort* __restrict__ WT) {
    int idx = blockIdx.x * 256 + threadIdx.x;
    int h = idx >> 13, u = (idx >> 7) & 63, d = idx & 127;
    WT[idx] = f2bf(Wmsg[((size_t)h * DC + d) * U_ + u]);
}

// ---------------------------------------------------------------------------
// Projections for ALL heads, 4 node-rows per block (W traffic /4).
// thread -> (isdst, h, u); hsrc/hdst layout [B,H,N,U] fp32.
__global__ void __launch_bounds__(512) proj_all(
    const float* __restrict__ prev, const float* __restrict__ Wsrc,
    const float* __restrict__ Wdst, float* __restrict__ hsrc,
    float* __restrict__ hdst)
{
    __shared__ float rows[4 * DP];
    const int tid = threadIdx.x;
    const int bn0 = blockIdx.x * 4;
    for (int e = tid; e < 4 * DP; e += 512) rows[e] = prev[(size_t)bn0 * DP + e];
    __syncthreads();
    const int u = tid & 63;
    const int h = (tid >> 6) & 3;
    const int isdst = tid >> 8;
    const float* W = (isdst ? Wdst : Wsrc) + (size_t)h * DP * U_;
    float a0 = 0.f, a1 = 0.f, a2 = 0.f, a3 = 0.f;
#pragma unroll 4
    for (int d = 0; d < DP; ++d) {
        float w = W[d * U_ + u];
        a0 = fmaf(rows[d], w, a0);
        a1 = fmaf(rows[DP + d], w, a1);
        a2 = fmaf(rows[2 * DP + d], w, a2);
        a3 = fmaf(rows[3 * DP + d], w, a3);
    }
    float acc[4] = {a0, a1, a2, a3};
    float* o = isdst ? hdst : hsrc;
#pragma unroll
    for (int r = 0; r < 4; ++r) {
        int bn = bn0 + r, b = bn / N_, n = bn - b * N_;
        o[(((size_t)b * H_ + h) * N_ + n) * U_ + u] = acc[r];
    }
}

// ---------------------------------------------------------------------------
// Scores + softmax, 4 i-rows per block, all heads in grid. bf16 output into
// padded attnB[b][h][512][512] (pads pre-zeroed).
__global__ void __launch_bounds__(512) attn_softmax(
    const float* __restrict__ hsrc, const float* __restrict__ hdst,
    const float* __restrict__ a_all, ushort* __restrict__ attnB)
{
    const int i0 = blockIdx.x * 4, b = blockIdx.y, h = blockIdx.z;
    const int tid = threadIdx.x;
    __shared__ float s_src[4][U_];
    __shared__ float s_a[U_];
    __shared__ float red[8];
    __shared__ float s_b;

    if (tid < 256)
        s_src[tid >> 6][tid & 63] =
            hsrc[(((size_t)b * H_ + h) * N_ + i0 + (tid >> 6)) * U_ + (tid & 63)];
    else if (tid < 320)
        s_a[tid - 256] = a_all[h * U_ + (tid - 256)];
    __syncthreads();

    const int j = tid;
    const bool valid = j < N_;
    float4 dj[16];
    if (valid) {
        const float4* dp =
            (const float4*)&hdst[(((size_t)b * H_ + h) * N_ + j) * U_];
#pragma unroll
        for (int k = 0; k < 16; ++k) dj[k] = dp[k];
    }

    float sc[4];
#pragma unroll
    for (int i = 0; i < 4; ++i) {
        float s = 0.f;
        if (valid) {
#pragma unroll
            for (int k = 0; k < 16; ++k) {
                float4 v = dj[k];
                float x;
                x = s_src[i][4 * k + 0] + v.x; x = x >= 0.f ? x : 0.2f * x; s = fmaf(x, s_a[4 * k + 0], s);
                x = s_src[i][4 * k + 1] + v.y; x = x >= 0.f ? x : 0.2f * x; s = fmaf(x, s_a[4 * k + 1], s);
                x = s_src[i][4 * k + 2] + v.z; x = x >= 0.f ? x : 0.2f * x; s = fmaf(x, s_a[4 * k + 2], s);
                x = s_src[i][4 * k + 3] + v.w; x = x >= 0.f ? x : 0.2f * x; s = fmaf(x, s_a[4 * k + 3], s);
            }
        }
        sc[i] = valid ? s : -1e30f;
    }

    const int wave = tid >> 6, lane = tid & 63;
    for (int i = 0; i < 4; ++i) {
        float m = sc[i];
        for (int off = 1; off < 64; off <<= 1) m = fmaxf(m, __shfl_xor(m, off));
        if (lane == 0) red[wave] = m;
        __syncthreads();
        if (tid == 0) {
            float mm = red[0];
            for (int w = 1; w < 8; ++w) mm = fmaxf(mm, red[w]);
            s_b = mm;
        }
        __syncthreads();
        float e = valid ? __expf(sc[i] - s_b) : 0.f;
        float sm = e;
        for (int off = 1; off < 64; off <<= 1) sm += __shfl_xor(sm, off);
        __syncthreads();
        if (lane == 0) red[wave] = sm;
        __syncthreads();
        if (tid == 0) {
            float ss = 0.f;
            for (int w = 0; w < 8; ++w) ss += red[w];
            s_b = ss;
        }
        __syncthreads();
        if (valid)
            attnB[(((size_t)b * H_ + h) * NP + i0 + i) * NP + j] = f2bf(e / s_b);
        __syncthreads();
    }
}

// ---------------------------------------------------------------------------
// msgT[b][col=t*64+u][m] = bf16( sum_d curr[b,t,m,d] * Wmsg_h[d,u] )
// MFMA GEMM: M-dim = m (128/block), N-dim = u (64), K = d (128, single shot).
// A = curr rows (fp32->bf16 on the fly), B = WT rows (pre-transposed bf16).
__global__ void __launch_bounds__(256) msg_mfma(
    const float* __restrict__ curr, const ushort* __restrict__ WTh,
    ushort* __restrict__ msgT)
{
    __shared__ ushort As[128 * 136];  // [m][d] pad+8
    __shared__ ushort Bs[64 * 136];   // [u][d] pad+8
    const int tid = threadIdx.x;
    const int m0 = blockIdx.x * 128, t = blockIdx.y, b = blockIdx.z;

    const float* cbase = curr + (size_t)(b * T_ + t) * N_ * DC;
#pragma unroll
    for (int it = 0; it < 16; ++it) {
        int e = it * 1024 + tid * 4;
        int r = e >> 7, c = e & 127;
        int gm = m0 + r;
        float4 v;
        v.x = v.y = v.z = v.w = 0.f;
        if (gm < N_) v = *(const float4*)&cbase[(size_t)gm * DC + c];
        ushort4 o;
        o.x = f2bf(v.x); o.y = f2bf(v.y); o.z = f2bf(v.z); o.w = f2bf(v.w);
        *(ushort4*)&As[r * 136 + c] = o;
    }
#pragma unroll
    for (int it = 0; it < 4; ++it) {
        int e = it * 2048 + tid * 8;
        int u = e >> 7, d = e & 127;
        *(uint4*)&Bs[u * 136 + d] = *(const uint4*)&WTh[u * 128 + d];
    }
    __syncthreads();

    const int wave = tid >> 6, lane = tid & 63;
    const int r15 = lane & 15, quad = lane >> 4;
    const int wm = wave >> 1, wu = wave & 1;  // wave tile: 64(m) x 32(u)

    f32x4 acc[4][2] = {};
#pragma unroll
    for (int ks = 0; ks < 4; ++ks) {
        bf16x8 af[4], bg[2];
#pragma unroll
        for (int f = 0; f < 4; ++f)
            af[f] = *(const bf16x8*)&As[(wm * 64 + f * 16 + r15) * 136 + ks * 32 + quad * 8];
#pragma unroll
        for (int g = 0; g < 2; ++g)
            bg[g] = *(const bf16x8*)&Bs[(wu * 32 + g * 16 + r15) * 136 + ks * 32 + quad * 8];
#pragma unroll
        for (int f = 0; f < 4; ++f)
#pragma unroll
            for (int g = 0; g < 2; ++g)
                acc[f][g] = __builtin_amdgcn_mfma_f32_16x16x32_bf16(af[f], bg[g], acc[f][g], 0, 0, 0);
    }

#pragma unroll
    for (int f = 0; f < 4; ++f)
#pragma unroll
        for (int g = 0; g < 2; ++g) {
            int m = m0 + wm * 64 + f * 16 + quad * 4;  // D rows = m (4 consecutive)
            int u = wu * 32 + g * 16 + r15;            // D col  = u
            int col = t * U_ + u;
            ushort4 o;
            o.x = f2bf(acc[f][g][0]); o.y = f2bf(acc[f][g][1]);
            o.z = f2bf(acc[f][g][2]); o.w = f2bf(acc[f][g][3]);
            *(ushort4*)&msgT[((size_t)b * COLS + col) * NP + m] = o;
        }
}

// ---------------------------------------------------------------------------
// out[b,t,i,u] (+)= 0.25 * sum_m attn[b,h,i,m] * msgT[b,t*64+u,m]
// MFMA GEMM per head: M-dim = col (64 = one t), N-dim = i (64), K = m (512).
// A = msgT rows, B = attn rows -- both contiguous 16B staging, b128 frag reads.
__global__ void __launch_bounds__(256) gemm_mfma(
    const ushort* __restrict__ msgT, const ushort* __restrict__ attnB,
    float* __restrict__ out, int h, int init)
{
    __shared__ ushort As[64 * 72];  // [col][k] pad+8
    __shared__ ushort Bs[64 * 72];  // [i][k]   pad+8
    const int tid = threadIdx.x;
    const int ct = blockIdx.x, it = blockIdx.y, b = blockIdx.z;

    const ushort* Ab = msgT + ((size_t)b * COLS + ct * 64) * NP;
    const ushort* Bb = attnB + (((size_t)b * H_ + h) * NP + it * 64) * NP;

    const int wave = tid >> 6, lane = tid & 63;
    const int r15 = lane & 15, quad = lane >> 4;
    const int wm = wave >> 1, wn = wave & 1;  // wave tile: 32(col) x 32(i)
    const int srow = tid >> 3, scol = (tid & 7) * 8;

    f32x4 acc[2][2] = {};
    for (int kk = 0; kk < NP; kk += 64) {
#pragma unroll
        for (int it2 = 0; it2 < 2; ++it2) {
            int rr = it2 * 32 + srow;
            *(uint4*)&As[rr * 72 + scol] = *(const uint4*)&Ab[(size_t)rr * NP + kk + scol];
            *(uint4*)&Bs[rr * 72 + scol] = *(const uint4*)&Bb[(size_t)rr * NP + kk + scol];
        }
        __syncthreads();
#pragma unroll
        for (int ks = 0; ks < 2; ++ks) {
            bf16x8 af[2], bg[2];
#pragma unroll
            for (int f = 0; f < 2; ++f)
                af[f] = *(const bf16x8*)&As[(wm * 32 + f * 16 + r15) * 72 + ks * 32 + quad * 8];
#pragma unroll
            for (int g = 0; g < 2; ++g)
                bg[g] = *(const bf16x8*)&Bs[(wn * 32 + g * 16 + r15) * 72 + ks * 32 + quad * 8];
#pragma unroll
            for (int f = 0; f < 2; ++f)
#pragma unroll
                for (int g = 0; g < 2; ++g)
                    acc[f][g] = __builtin_amdgcn_mfma_f32_16x16x32_bf16(af[f], bg[g], acc[f][g], 0, 0, 0);
        }
        __syncthreads();
    }

    const int t = ct;
#pragma unroll
    for (int f = 0; f < 2; ++f)
#pragma unroll
        for (int g = 0; g < 2; ++g) {
            int u = wm * 32 + f * 16 + quad * 4;       // D rows = u (4 consecutive)
            int i = it * 64 + wn * 32 + g * 16 + r15;  // D col  = i
            if (i < N_) {
                float* op = out + (((size_t)b * T_ + t) * N_ + i) * U_ + u;
                float4 v;
                v.x = acc[f][g][0] * 0.25f; v.y = acc[f][g][1] * 0.25f;
                v.z = acc[f][g][2] * 0.25f; v.w = acc[f][g][3] * 0.25f;
                if (!init) {
                    float4 old = *(const float4*)op;
                    v.x += old.x; v.y += old.y; v.z += old.z; v.w += old.w;
                }
                *(float4*)op = v;
            }
        }
}

// ---------------------------------------------------------------------------
extern "C" void kernel_launch(void* const* d_in, const int* in_sizes, int n_in,
                              void* d_out, int out_size, void* d_ws, size_t ws_size,
                              hipStream_t stream)
{
    const float* prev = (const float*)d_in[0];   // [B,N,DP]
    const float* curr = (const float*)d_in[1];   // [B,T,N,DC]
    const float* Wsrc = (const float*)d_in[2];   // [H,DP,U]
    const float* Wdst = (const float*)d_in[3];   // [H,DP,U]
    const float* avec = (const float*)d_in[4];   // [H,U,1]
    const float* Wmsg = (const float*)d_in[5];   // [H,DC,U]
    float* out = (float*)d_out;                  // [B,T,N,U]

    ushort* attnB = (ushort*)d_ws;                         // [B,H,512,512] bf16
    ushort* msgT  = attnB + (size_t)B_ * H_ * NP * NP;     // [B,2048,512]  bf16
    ushort* WT    = msgT + (size_t)B_ * COLS * NP;         // [H,64,128]    bf16
    float*  hsrc  = (float*)(WT + (size_t)H_ * U_ * DC);   // [B,H,N,64] fp32
    float*  hdst  = hsrc + (size_t)B_ * H_ * N_ * U_;

    const int n16 = (int)(((size_t)B_ * H_ * NP * NP + (size_t)B_ * COLS * NP) * 2 / 16);
    zero_fill<<<2048, 256, 0, stream>>>((uint4*)attnB, n16);
    prep_wT<<<128, 256, 0, stream>>>(Wmsg, WT);
    proj_all<<<1000, 512, 0, stream>>>(prev, Wsrc, Wdst, hsrc, hdst);
    attn_softmax<<<dim3(125, B_, H_), 512, 0, stream>>>(hsrc, hdst, avec, attnB);

    for (int h = 0; h < H_; ++h) {
        msg_mfma<<<dim3(4, T_, B_), 256, 0, stream>>>(curr, WT + (size_t)h * U_ * DC, msgT);
        gemm_mfma<<<dim3(32, 8, B_), 256, 0, stream>>>(msgT, attnB, out, h, h == 0 ? 1 : 0);
    }
}